// Round 9
// baseline (22.580 us; speedup 1.0000x reference)
//
#include <hip/hip_runtime.h>
#include <math.h>

// ---------------------------------------------------------------------------
// WeightedRandomSampler (inverse-CDF multinomial), 2-kernel design, GRP=4:
//   K1 gsum_kernel  : one thread per float4 group -> gsum[G] (G = ceil(V/4)).
//   K2 sample_kernel: per block:
//       stage gsum into LDS coalesced (float4) -> barrier ->
//       each thread reads GPT contiguous group sums from LDS (2-way bank
//       aliasing = free) -> block scan -> padded group-CDF sS[phys(i)],
//       phys(i) = i + i/32 (de-conflicts the pow2-stride bsearch probes).
//     Per sample: 14-level branchless LDS bsearch -> group g; ONE float4
//       load of freq[4g..4g+4) (exactly one L1 line transaction per sample,
//       4x fewer than GRP=16's four) -> prefix + compare-count ->
//       searchsorted(cdf, key, 'right'); clip; float out.
//   Rationale (r8 post-mortem): refine vmem gather TRANSACTIONS dominate;
//   GRP=4 minimizes them at the cost of +2 cheap LDS probe levels.
// ---------------------------------------------------------------------------

#define GRP 4         // freq elements per group = one float4
#define TPB 512       // sampler threads per block (8 waves)
#define SPT 4         // samples per thread -> 512 blocks for N=2^20

__device__ __forceinline__ int physIdx(int i) { return i + (i >> 5); }

__global__ __launch_bounds__(256) void gsum_kernel(const float* __restrict__ freq,
                                                   int V, float* __restrict__ gsum) {
    const int g = blockIdx.x * 256 + threadIdx.x;     // group == float4 index
    const int G = (V + 3) >> 2;
    if (g >= G) return;
    const int base = g * 4;
    float s = 0.f;
    if (base + 3 < V) {
        const float4 v = *reinterpret_cast<const float4*>(freq + base);
        s = v.x + v.y + v.z + v.w;
    } else {
        for (int j = 0; j < 4; ++j)
            if (base + j < V) s += freq[base + j];
    }
    gsum[g] = s;
}

template <int PAD>
__global__ __launch_bounds__(TPB) void sample_kernel(const float* __restrict__ freq,
                                                     const float* __restrict__ u,
                                                     const float* __restrict__ gsum,
                                                     float* __restrict__ out,
                                                     int N, int V, int G) {
    constexpr int GPTM = PAD / TPB;          // max groups per thread
    __shared__ float sS[PAD + (PAD >> 5)];   // temp gsum stage, then padded CDF
    __shared__ float wsum[TPB / 64];
    const int t = threadIdx.x;
    const int lane = t & 63;
    const int w = t >> 6;
    const int GPT = (G + TPB - 1) / TPB;     // 25 for G=12565

    // hoisted sample load: issue HBM read before the scan phases
    const int gid = blockIdx.x * TPB + t;
    const long long i0 = (long long)gid * SPT;
    float uk[SPT];
    const bool full = (i0 + SPT <= N);
    if (full) {
        const float4 A = *reinterpret_cast<const float4*>(u + i0);
        uk[0] = A.x; uk[1] = A.y; uk[2] = A.z; uk[3] = A.w;
    } else {
#pragma unroll
        for (int s = 0; s < SPT; ++s) uk[s] = (i0 + s < N) ? u[i0 + s] : 0.f;
    }

    // ---- phase A0: stage gsum into LDS, coalesced float4 ----
    const int G4 = G >> 2;
    const float4* gs4 = reinterpret_cast<const float4*>(gsum);
    float4* sS4 = reinterpret_cast<float4*>(sS);
    for (int i = t; i < G4; i += TPB) sS4[i] = gs4[i];
    for (int i = (G4 << 2) + t; i < G; i += TPB) sS[i] = gsum[i];
    __syncthreads();

    // ---- phase A1: per-thread local scan of GPT contiguous group sums ----
    const int g0 = t * GPT;
    float ls[GPTM];
    float runv = 0.f;
#pragma unroll
    for (int k = 0; k < GPTM; ++k) {
        float s = 0.f;
        if (k < GPT) { const int g = g0 + k; if (g < G) s = sS[g]; }
        runv += s;
        ls[k] = runv;
    }
    float sc = runv;                         // wave-inclusive scan of totals
#pragma unroll
    for (int off = 1; off <= 32; off <<= 1) {
        const float v = __shfl_up(sc, off);
        if (lane >= off) sc += v;
    }
    if (lane == 63) wsum[w] = sc;
    __syncthreads();                         // wsum visible AND temp reads done
    float tbase = sc - runv;                 // exclusive base for this thread
    for (int k = 0; k < w; ++k) tbase += wsum[k];

    // ---- phase A2: write padded group-CDF (overwrites temp region) ----
#pragma unroll
    for (int k = 0; k < GPTM; ++k) {
        if (k < GPT) { const int g = g0 + k; if (g < G) sS[physIdx(g)] = tbase + ls[k]; }
    }
    for (int i = G + t; i < PAD; i += TPB) sS[physIdx(i)] = INFINITY;
    __syncthreads();

    if (i0 >= N) return;                     // after all barriers

    const float total = sS[physIdx(G - 1)];  // broadcast LDS read

    // ---- phase B: sample ----
    float ok[SPT];
#pragma unroll
    for (int s = 0; s < SPT; ++s) {
        const float key = uk[s] * total;

        // branchless "count of entries <= key" over PAD sorted values
        int pos = -1;
#pragma unroll
        for (int step = PAD >> 1; step >= 1; step >>= 1) {
            const int j = pos + step;
            pos += (sS[physIdx(j)] <= key) ? step : 0;
        }
        int g = pos + 1;                     // group holding the boundary
        g = (g > G - 1) ? (G - 1) : g;
        const float base = (g > 0) ? sS[physIdx(g - 1)] : 0.f;
        const int eb = g << 2;

        float r = base;
        int cnt = 0;
        if (eb + 4 <= V) {
            const float4 f = *reinterpret_cast<const float4*>(freq + eb);
            r += f.x; cnt += (r <= key);
            r += f.y; cnt += (r <= key);
            r += f.z; cnt += (r <= key);
            r += f.w; cnt += (r <= key);
        } else {                             // tail group, guarded
            for (int j = 0; j < 4; ++j) {
                const int idx = eb + j;
                if (idx < V) { r += freq[idx]; cnt += (r <= key); }
            }
        }
        int ans = eb + cnt;                  // searchsorted 'right'
        ans = (ans > V - 1) ? (V - 1) : ans; // clip like reference
        ok[s] = (float)ans;
    }

    if (full) {
        *reinterpret_cast<float4*>(out + i0) = make_float4(ok[0], ok[1], ok[2], ok[3]);
    } else {
        for (int s = 0; s < SPT; ++s)
            if (i0 + s < N) out[i0 + s] = ok[s];
    }
}

extern "C" void kernel_launch(void* const* d_in, const int* in_sizes, int n_in,
                              void* d_out, int out_size, void* d_ws, size_t ws_size,
                              hipStream_t stream) {
    const float* freq = (const float*)d_in[0];
    const float* u    = (const float*)d_in[1];
    float* out        = (float*)d_out;
    const int V = in_sizes[0];
    const int N = in_sizes[1];
    const int G = (V + GRP - 1) / GRP;                 // 12565 for V=50257

    float* gsum = (float*)d_ws;                        // G floats in ws

    hipLaunchKernelGGL(gsum_kernel, dim3((G + 255) / 256), dim3(256), 0, stream,
                       freq, V, gsum);

    const int NB = (N + TPB * SPT - 1) / (TPB * SPT);  // 512 for N=2^20
    if (G < 2048) {
        hipLaunchKernelGGL(sample_kernel<2048>, dim3(NB), dim3(TPB), 0, stream,
                           freq, u, gsum, out, N, V, G);
    } else if (G < 4096) {
        hipLaunchKernelGGL(sample_kernel<4096>, dim3(NB), dim3(TPB), 0, stream,
                           freq, u, gsum, out, N, V, G);
    } else if (G < 8192) {
        hipLaunchKernelGGL(sample_kernel<8192>, dim3(NB), dim3(TPB), 0, stream,
                           freq, u, gsum, out, N, V, G);
    } else {
        hipLaunchKernelGGL(sample_kernel<16384>, dim3(NB), dim3(TPB), 0, stream,
                           freq, u, gsum, out, N, V, G);
    }
}